// Round 1
// baseline (129.002 us; speedup 1.0000x reference)
//
#include <hip/hip_runtime.h>

#define KS 7
#define KK 49
#define PADK 3
#define CIN 128
#define CR 32
#define HH 64
#define WW 64
#define HWSZ 4096
#define NB 4

// ---------------- Kernel 1: generate per-pixel involution kernels ----------
// grid 256 blocks x 256 threads. Block = 64 consecutive pixels (one w-row).
// Wave q (=tid>>6) accumulates c-range [q*32, q*32+32) of the 128->32 matmul,
// partials reduced through padded LDS, then BN+ReLU and the 32->49 matmul
// (taps split 13/13/13/10 across the 4 waves).
__global__ __launch_bounds__(256) void gen_kernel(
    const float* __restrict__ x, const float* __restrict__ w1,
    const float* __restrict__ b1, const float* __restrict__ bn_gamma,
    const float* __restrict__ bn_beta, const float* __restrict__ bn_mean,
    const float* __restrict__ bn_var, const float* __restrict__ w2,
    const float* __restrict__ b2, float* __restrict__ ker)
{
    __shared__ float fs[4][64][33];   // padded: bank = (lane+o)%32, conflict-free
    const int tid  = threadIdx.x;
    const int lane = tid & 63;
    const int q    = tid >> 6;        // wave-uniform
    const int pix  = blockIdx.x * 64 + lane;
    const int b    = pix >> 12;
    const int hw   = pix & 4095;

    const float* xp = x + ((size_t)b * CIN) * HWSZ + hw;

    float f[CR];
#pragma unroll
    for (int o = 0; o < CR; ++o) f[o] = 0.f;

    const int cbeg = q * 32;
#pragma unroll 8
    for (int ci = 0; ci < 32; ++ci) {
        const int c = cbeg + ci;
        const float xv = xp[(size_t)c * HWSZ];   // coalesced across lanes
#pragma unroll
        for (int o = 0; o < CR; ++o)
            f[o] += w1[o * CIN + c] * xv;        // uniform -> scalar loads
    }

#pragma unroll
    for (int o = 0; o < CR; ++o) fs[q][lane][o] = f[o];
    __syncthreads();

    float fr[CR];
#pragma unroll
    for (int o = 0; o < CR; ++o)
        fr[o] = fs[0][lane][o] + fs[1][lane][o] + fs[2][lane][o] + fs[3][lane][o];

#pragma unroll
    for (int o = 0; o < CR; ++o) {
        const float sc = bn_gamma[o] * rsqrtf(bn_var[o] + 1e-5f);
        const float v  = (fr[o] + b1[o]) * sc + (bn_beta[o] - bn_mean[o] * sc);
        fr[o] = fmaxf(v, 0.f);
    }

    const int pbeg = q * 13;
    const int pend = (pbeg + 13 < KK) ? (pbeg + 13) : KK;
    float* kout = ker + ((size_t)b * KK) * HWSZ + hw;
    for (int p = pbeg; p < pend; ++p) {
        float s = b2[p];
#pragma unroll
        for (int o = 0; o < CR; ++o)
            s += w2[p * CR + o] * fr[o];         // uniform -> scalar loads
        kout[(size_t)p * HWSZ] = s;              // coalesced
    }
}

// ---------------- Kernel 2: apply the 7x7 gather ---------------------------
// grid 256 blocks = b(4) x tile(4x4 of 16x16 pixels) x csplit(4 of 32 ch).
// Thread = pixel; its 49 ker values live in VGPRs and are reused across all
// 32 channels it owns. Per 4-channel group: stage 22x22x4 halo to LDS in
// channel-interleaved layout -> inner loop is ds_read_b128 (4 ch per read).
__global__ __launch_bounds__(256) void inv_gather(
    const float* __restrict__ x, const float* __restrict__ ker,
    float* __restrict__ out)
{
    __shared__ float xs[22 * 22 * 4];   // [spatial][c4], 7744 B, 16B-aligned rows

    const int bid = blockIdx.x;
    const int cs  = bid & 3;
    const int tw  = (bid >> 2) & 3;
    const int th  = (bid >> 4) & 3;
    const int b   = bid >> 6;

    const int h0 = th * 16, w0 = tw * 16, c0 = cs * 32;
    const int tid = threadIdx.x;
    const int tx = tid & 15, ty = tid >> 4;
    const int h = h0 + ty, w = w0 + tx;

    // load this pixel's 49 kernel values into VGPRs
    float kr[KK];
    const float* kp = ker + ((size_t)b * KK) * HWSZ + h * WW + w;
#pragma unroll
    for (int p = 0; p < KK; ++p) kr[p] = kp[(size_t)p * HWSZ];

    const size_t xbase = (size_t)b * CIN * HWSZ;
    const int spbase = ty * 22 + tx;

    for (int cg = 0; cg < 8; ++cg) {
        const int cbase = c0 + cg * 4;

        __syncthreads();   // previous compute done before overwriting xs
        // stage halo: 1936 elements, spatial-major so global reads coalesce
        for (int e = tid; e < 484 * 4; e += 256) {
            const int cc  = e / 484;
            const int sp  = e - cc * 484;
            const int row = sp / 22;
            const int col = sp - row * 22;
            const int gr = h0 - 3 + row;
            const int gc = w0 - 3 + col;
            float v = 0.f;
            if ((unsigned)gr < 64u && (unsigned)gc < 64u)
                v = x[xbase + (size_t)(cbase + cc) * HWSZ + gr * WW + gc];
            xs[sp * 4 + cc] = v;
        }
        __syncthreads();

        float ax = 0.f, ay = 0.f, az = 0.f, aw = 0.f;
#pragma unroll
        for (int i = 0; i < KS; ++i) {
#pragma unroll
            for (int j = 0; j < KS; ++j) {
                const float4 xv = *reinterpret_cast<const float4*>(
                    &xs[(spbase + i * 22 + j) * 4]);
                const float k = kr[i * KS + j];
                ax += k * xv.x; ay += k * xv.y; az += k * xv.z; aw += k * xv.w;
            }
        }

        const size_t obase = xbase + (size_t)cbase * HWSZ + h * WW + w;
        out[obase]            = ax;
        out[obase + HWSZ]     = ay;
        out[obase + 2 * HWSZ] = az;
        out[obase + 3 * HWSZ] = aw;
    }
}

extern "C" void kernel_launch(void* const* d_in, const int* in_sizes, int n_in,
                              void* d_out, int out_size, void* d_ws, size_t ws_size,
                              hipStream_t stream) {
    const float* x        = (const float*)d_in[0];
    const float* w1       = (const float*)d_in[1];
    const float* b1       = (const float*)d_in[2];
    const float* bn_gamma = (const float*)d_in[3];
    const float* bn_beta  = (const float*)d_in[4];
    const float* bn_mean  = (const float*)d_in[5];
    const float* bn_var   = (const float*)d_in[6];
    const float* w2       = (const float*)d_in[7];
    const float* b2       = (const float*)d_in[8];
    float* ker = (float*)d_ws;          // [4,49,64,64] fp32 = 3.2 MB
    float* out = (float*)d_out;

    gen_kernel<<<256, 256, 0, stream>>>(x, w1, b1, bn_gamma, bn_beta,
                                        bn_mean, bn_var, w2, b2, ker);
    inv_gather<<<256, 256, 0, stream>>>(x, ker, out);
}

// Round 3
// 102.944 us; speedup vs baseline: 1.2531x; 1.2531x over previous
//
#include <hip/hip_runtime.h>

#define KS 7
#define KK 49
#define CIN 128
#define CR 32
#define WW 64
#define HWSZ 4096

// ---------------- Kernel 1: generate per-pixel involution kernels ----------
// grid 256 blocks x 256 threads. Block = 64 consecutive pixels (one w-row).
// Wave q (=tid>>6) accumulates c-range [q*32, q*32+32) of the 128->32 matmul,
// partials reduced through padded LDS, then BN+ReLU and the 32->49 matmul
// (taps split 13/13/13/10 across the 4 waves).
__global__ __launch_bounds__(256) void gen_kernel(
    const float* __restrict__ x, const float* __restrict__ w1,
    const float* __restrict__ b1, const float* __restrict__ bn_gamma,
    const float* __restrict__ bn_beta, const float* __restrict__ bn_mean,
    const float* __restrict__ bn_var, const float* __restrict__ w2,
    const float* __restrict__ b2, float* __restrict__ ker)
{
    __shared__ float fs[4][64][33];   // padded: conflict-free
    const int tid  = threadIdx.x;
    const int lane = tid & 63;
    const int q    = tid >> 6;        // wave-uniform
    const int pix  = blockIdx.x * 64 + lane;
    const int b    = pix >> 12;
    const int hw   = pix & 4095;

    const float* xp = x + ((size_t)b * CIN) * HWSZ + hw;

    float f[CR];
#pragma unroll
    for (int o = 0; o < CR; ++o) f[o] = 0.f;

    const int cbeg = q * 32;
#pragma unroll 8
    for (int ci = 0; ci < 32; ++ci) {
        const int c = cbeg + ci;
        const float xv = xp[(size_t)c * HWSZ];   // coalesced across lanes
#pragma unroll
        for (int o = 0; o < CR; ++o)
            f[o] += w1[o * CIN + c] * xv;        // uniform -> scalar loads
    }

#pragma unroll
    for (int o = 0; o < CR; ++o) fs[q][lane][o] = f[o];
    __syncthreads();

    float fr[CR];
#pragma unroll
    for (int o = 0; o < CR; ++o)
        fr[o] = fs[0][lane][o] + fs[1][lane][o] + fs[2][lane][o] + fs[3][lane][o];

#pragma unroll
    for (int o = 0; o < CR; ++o) {
        const float sc = bn_gamma[o] * rsqrtf(bn_var[o] + 1e-5f);
        const float v  = (fr[o] + b1[o]) * sc + (bn_beta[o] - bn_mean[o] * sc);
        fr[o] = fmaxf(v, 0.f);
    }

    const int pbeg = q * 13;
    const int pend = (pbeg + 13 < KK) ? (pbeg + 13) : KK;
    float* kout = ker + ((size_t)b * KK) * HWSZ + hw;
    for (int p = pbeg; p < pend; ++p) {
        float s = b2[p];
#pragma unroll
        for (int o = 0; o < CR; ++o)
            s += w2[p * CR + o] * fr[o];         // uniform -> scalar loads
        kout[(size_t)p * HWSZ] = s;              // coalesced
    }
}

// ---------------- Kernel 2: apply the 7x7 gather ---------------------------
// grid 512 blocks = b(4) x th(4) x tw(4) x csplit(8 of 16 ch).
// -> 2 blocks/CU, 8 waves/CU (vs 1 block/CU before).
// Thread = pixel; 49 ker values in VGPRs, reused across 16 channels.
// Per 4-channel group: halo 22x22x4 in LDS [spatial][c4], double-buffered;
// staging of cg+1 issued BEFORE compute of cg so global latency hides under
// the 49x ds_read_b128 + 196 FMA compute. One __syncthreads per iteration.
__global__ __launch_bounds__(256) void inv_gather(
    const float* __restrict__ x, const float* __restrict__ ker,
    float* __restrict__ out)
{
    __shared__ float xs[2][484 * 4];   // 2 x 7744 B

    const int bid = blockIdx.x;
    const int cs  = bid & 7;
    const int tw  = (bid >> 3) & 3;
    const int th  = (bid >> 5) & 3;
    const int b   = bid >> 7;

    const int h0 = th * 16, w0 = tw * 16, c0 = cs * 16;
    const int tid = threadIdx.x;
    const int tx = tid & 15, ty = tid >> 4;
    const int h = h0 + ty, w = w0 + tx;

    // this pixel's 49 kernel values -> VGPRs (reused for all 16 channels)
    float kr[KK];
    const float* kp = ker + ((size_t)b * KK) * HWSZ + h * WW + w;
#pragma unroll
    for (int p = 0; p < KK; ++p) kr[p] = kp[(size_t)p * HWSZ];

    const size_t xbase = (size_t)b * CIN * HWSZ;
    const int spbase = ty * 22 + tx;

    // stage 22x22 halo of 4 channels into xs[buf] as [spatial][c4].
    // only division is by constant 22 (magic-mul); one ds_write_b128 per sp.
    auto stage = [&](int buf, int cbase) {
        for (int sp = tid; sp < 484; sp += 256) {
            const int row = sp / 22;
            const int col = sp - row * 22;
            const int gr = h0 - 3 + row;
            const int gc = w0 - 3 + col;
            float4 v = {0.f, 0.f, 0.f, 0.f};
            if ((unsigned)gr < 64u && (unsigned)gc < 64u) {
                const float* xp = &x[xbase + (size_t)cbase * HWSZ + gr * WW + gc];
                v.x = xp[0];
                v.y = xp[HWSZ];
                v.z = xp[2 * HWSZ];
                v.w = xp[3 * HWSZ];
            }
            *reinterpret_cast<float4*>(&xs[buf][sp * 4]) = v;
        }
    };

    stage(0, c0);
    __syncthreads();

    for (int cg = 0; cg < 4; ++cg) {
        const int cbase = c0 + cg * 4;
        if (cg < 3) stage((cg + 1) & 1, cbase + 4);   // prefetch next group

        float ax = 0.f, ay = 0.f, az = 0.f, aw = 0.f;
        const float* xb = &xs[cg & 1][0];
#pragma unroll
        for (int i = 0; i < KS; ++i) {
#pragma unroll
            for (int j = 0; j < KS; ++j) {
                const float4 xv = *reinterpret_cast<const float4*>(
                    &xb[(spbase + i * 22 + j) * 4]);
                const float k = kr[i * KS + j];
                ax += k * xv.x; ay += k * xv.y; az += k * xv.z; aw += k * xv.w;
            }
        }

        const size_t obase = xbase + (size_t)cbase * HWSZ + h * WW + w;
        out[obase]            = ax;
        out[obase + HWSZ]     = ay;
        out[obase + 2 * HWSZ] = az;
        out[obase + 3 * HWSZ] = aw;

        __syncthreads();   // staged buffer ready + safe to overwrite read buffer
    }
}

extern "C" void kernel_launch(void* const* d_in, const int* in_sizes, int n_in,
                              void* d_out, int out_size, void* d_ws, size_t ws_size,
                              hipStream_t stream) {
    const float* x        = (const float*)d_in[0];
    const float* w1       = (const float*)d_in[1];
    const float* b1       = (const float*)d_in[2];
    const float* bn_gamma = (const float*)d_in[3];
    const float* bn_beta  = (const float*)d_in[4];
    const float* bn_mean  = (const float*)d_in[5];
    const float* bn_var   = (const float*)d_in[6];
    const float* w2       = (const float*)d_in[7];
    const float* b2       = (const float*)d_in[8];
    float* ker = (float*)d_ws;          // [4,49,64,64] fp32 = 3.2 MB
    float* out = (float*)d_out;

    gen_kernel<<<256, 256, 0, stream>>>(x, w1, b1, bn_gamma, bn_beta,
                                        bn_mean, bn_var, w2, b2, ker);
    inv_gather<<<512, 256, 0, stream>>>(x, ker, out);
}

// Round 7
// 98.564 us; speedup vs baseline: 1.3088x; 1.0444x over previous
//
#include <hip/hip_runtime.h>

#define KS 7
#define KK 49
#define CIN 128
#define CR 32
#define WW 64
#define HWSZ 4096

// ---------------- Kernel 1: generate per-pixel involution kernels ----------
// grid 256 blocks x 512 threads (8 waves -> 2 waves/SIMD).
// Block = 64 consecutive pixels. Wave q (=tid>>6) accumulates c-range
// [q*16, q*16+16) of the 128->32 matmul. readfirstlane forces the weight
// bases into SGPRs so w1/w2 reads are true s_loads (1 SGPR read per VALU).
// Partials reduced via LDS (pad 36 keeps b128 alignment + even banks),
// BN+ReLU in-place, then the 32->49 matmul split 7/6/6/6/6/6/6/- by wave.
__global__ __launch_bounds__(512) void gen_kernel(
    const float* __restrict__ x, const float* __restrict__ w1,
    const float* __restrict__ b1, const float* __restrict__ bn_gamma,
    const float* __restrict__ bn_beta, const float* __restrict__ bn_mean,
    const float* __restrict__ bn_var, const float* __restrict__ w2,
    const float* __restrict__ b2, float* __restrict__ ker)
{
    __shared__ float fs[8][64][36];   // 73.7 KB
    const int tid  = threadIdx.x;
    const int lane = tid & 63;
    const int q    = tid >> 6;        // wave index 0..7
    const int pix  = blockIdx.x * 64 + lane;
    const int b    = pix >> 12;
    const int hw   = pix & 4095;

    const float* xp = x + ((size_t)b * CIN) * HWSZ + hw;

    // wave-uniform weight base, forced scalar
    const float* w1q = w1 + __builtin_amdgcn_readfirstlane(q * 16);

    float f[CR];
#pragma unroll
    for (int o = 0; o < CR; ++o) f[o] = 0.f;

#pragma unroll
    for (int ci = 0; ci < 16; ++ci) {
        const float xv = xp[(size_t)(q * 16 + ci) * HWSZ];   // coalesced
#pragma unroll
        for (int o = 0; o < CR; ++o)
            f[o] += w1q[o * CIN + ci] * xv;                  // s_load weights
    }

#pragma unroll
    for (int o = 0; o < CR; o += 4) {
        float4 v = {f[o], f[o + 1], f[o + 2], f[o + 3]};
        *reinterpret_cast<float4*>(&fs[q][lane][o]) = v;
    }
    __syncthreads();

    // thread (lane, q) reduces o-range [q*4, q*4+4) over the 8 partials
    const int ob = q * 4;
    float4 r = {0.f, 0.f, 0.f, 0.f};
#pragma unroll
    for (int g = 0; g < 8; ++g) {
        const float4 v = *reinterpret_cast<const float4*>(&fs[g][lane][ob]);
        r.x += v.x; r.y += v.y; r.z += v.z; r.w += v.w;
    }
    // BN (eval) + ReLU
    {
        float rr[4] = {r.x, r.y, r.z, r.w};
#pragma unroll
        for (int k = 0; k < 4; ++k) {
            const int o = ob + k;
            const float sc = bn_gamma[o] * rsqrtf(bn_var[o] + 1e-5f);
            const float v  = (rr[k] + b1[o]) * sc + (bn_beta[o] - bn_mean[o] * sc);
            rr[k] = fmaxf(v, 0.f);
        }
        float4 w = {rr[0], rr[1], rr[2], rr[3]};
        // in-place: only this thread ever touches fs[0][lane][ob..ob+4)
        *reinterpret_cast<float4*>(&fs[0][lane][ob]) = w;
    }
    __syncthreads();

    // matmul2: fr = fs[0][lane][0..31]; taps split 7,6,6,6,6,6,6,0 by wave
    float fr[CR];
#pragma unroll
    for (int o = 0; o < CR; o += 4) {
        const float4 v = *reinterpret_cast<const float4*>(&fs[0][lane][o]);
        fr[o] = v.x; fr[o + 1] = v.y; fr[o + 2] = v.z; fr[o + 3] = v.w;
    }

    const int p0 = (q == 0) ? 0 : q * 6 + 1;
    const int np = (q == 0) ? 7 : 6;   // q==7 -> p0=43,np=6 -> 43..48 ok
    const float* w2q = w2 + __builtin_amdgcn_readfirstlane(p0 * CR);
    float* kout = ker + ((size_t)b * KK) * HWSZ + hw;
#pragma unroll
    for (int pi = 0; pi < 7; ++pi) {
        if (pi >= np) break;           // wave-uniform branch
        float s = b2[p0 + pi];
#pragma unroll
        for (int o = 0; o < CR; ++o)
            s += w2q[pi * CR + o] * fr[o];                   // s_load weights
        kout[(size_t)(p0 + pi) * HWSZ] = s;                  // coalesced
    }
}

// ---------------- Kernel 2: apply the 7x7 gather ---------------------------
// grid 1024 blocks = b(4) x th(4) x tw(4) x csplit(16 of 8 ch)
// -> 4 blocks/CU, 16 waves/CU. Thread = pixel; 49 ker values in VGPRs,
// reused across its 8 channels. Single stage of the 22x22 halo for all 8
// channels into TWO [484][4] buffers (split keeps ds_read_b128 on the even
// 32-bank pattern), then ONE __syncthreads, then 49 taps x 2 b128 reads x
// 8 FMA with full ILP.
__global__ __launch_bounds__(256) void inv_gather(
    const float* __restrict__ x, const float* __restrict__ ker,
    float* __restrict__ out)
{
    __shared__ float xsA[484 * 4];   // ch 0..3 of this block's 8
    __shared__ float xsB[484 * 4];   // ch 4..7

    const int bid = blockIdx.x;
    const int cs  = bid & 15;
    const int tw  = (bid >> 4) & 3;
    const int th  = (bid >> 6) & 3;
    const int b   = bid >> 8;

    const int h0 = th * 16, w0 = tw * 16, c0 = cs * 8;
    const int tid = threadIdx.x;
    const int tx = tid & 15, ty = tid >> 4;
    const int h = h0 + ty, w = w0 + tx;

    // this pixel's 49 kernel values -> VGPRs (reused for all 8 channels)
    float kr[KK];
    const float* kp = ker + ((size_t)b * KK) * HWSZ + h * WW + w;
#pragma unroll
    for (int p = 0; p < KK; ++p) kr[p] = kp[(size_t)p * HWSZ];

    const size_t xbase = (size_t)b * CIN * HWSZ + (size_t)c0 * HWSZ;

    // stage halo: 484 positions x 2 channel-halves; unit e = (sp, half)
    for (int e = tid; e < 968; e += 256) {
        const int sp   = e >> 1;
        const int half = e & 1;
        const int row = sp / 22;
        const int col = sp - row * 22;
        const int gr = h0 - 3 + row;
        const int gc = w0 - 3 + col;
        float4 v = {0.f, 0.f, 0.f, 0.f};
        if ((unsigned)gr < 64u && (unsigned)gc < 64u) {
            const float* xp = &x[xbase + (size_t)(half * 4) * HWSZ + gr * WW + gc];
            v.x = xp[0];
            v.y = xp[HWSZ];
            v.z = xp[2 * HWSZ];
            v.w = xp[3 * HWSZ];
        }
        float* dst = half ? xsB : xsA;
        *reinterpret_cast<float4*>(&dst[sp * 4]) = v;
    }
    __syncthreads();

    float a0 = 0.f, a1 = 0.f, a2 = 0.f, a3 = 0.f;
    float a4 = 0.f, a5 = 0.f, a6 = 0.f, a7 = 0.f;
    const int spbase = ty * 22 + tx;
#pragma unroll
    for (int i = 0; i < KS; ++i) {
#pragma unroll
        for (int j = 0; j < KS; ++j) {
            const int sp = spbase + i * 22 + j;
            const float k = kr[i * KS + j];
            const float4 va = *reinterpret_cast<const float4*>(&xsA[sp * 4]);
            const float4 vb = *reinterpret_cast<const float4*>(&xsB[sp * 4]);
            a0 += k * va.x; a1 += k * va.y; a2 += k * va.z; a3 += k * va.w;
            a4 += k * vb.x; a5 += k * vb.y; a6 += k * vb.z; a7 += k * vb.w;
        }
    }

    const size_t obase = xbase + h * WW + w;
    out[obase]            = a0;
    out[obase + HWSZ]     = a1;
    out[obase + 2 * HWSZ] = a2;
    out[obase + 3 * HWSZ] = a3;
    out[obase + 4 * HWSZ] = a4;
    out[obase + 5 * HWSZ] = a5;
    out[obase + 6 * HWSZ] = a6;
    out[obase + 7 * HWSZ] = a7;
}

extern "C" void kernel_launch(void* const* d_in, const int* in_sizes, int n_in,
                              void* d_out, int out_size, void* d_ws, size_t ws_size,
                              hipStream_t stream) {
    const float* x        = (const float*)d_in[0];
    const float* w1       = (const float*)d_in[1];
    const float* b1       = (const float*)d_in[2];
    const float* bn_gamma = (const float*)d_in[3];
    const float* bn_beta  = (const float*)d_in[4];
    const float* bn_mean  = (const float*)d_in[5];
    const float* bn_var   = (const float*)d_in[6];
    const float* w2       = (const float*)d_in[7];
    const float* b2       = (const float*)d_in[8];
    float* ker = (float*)d_ws;          // [4,49,64,64] fp32 = 3.2 MB
    float* out = (float*)d_out;

    gen_kernel<<<256, 512, 0, stream>>>(x, w1, b1, bn_gamma, bn_beta,
                                        bn_mean, bn_var, w2, b2, ker);
    inv_gather<<<1024, 256, 0, stream>>>(x, ker, out);
}

// Round 9
// 98.176 us; speedup vs baseline: 1.3140x; 1.0040x over previous
//
#include <hip/hip_runtime.h>

#define KS 7
#define KK 49
#define CIN 128
#define CR 32
#define WW 64
#define HWSZ 4096

// ---------------- Kernel 1: generate per-pixel involution kernels ----------
// grid 256 blocks x 512 threads (8 waves -> 2 waves/SIMD).
// Block = 64 consecutive pixels. Wave q (=tid>>6) accumulates c-range
// [q*16, q*16+16) of the 128->32 matmul; weight bases forced to SGPR via
// readfirstlane. LDS reduction, BN+ReLU, then 32->49 split across waves.
__global__ __launch_bounds__(512) void gen_kernel(
    const float* __restrict__ x, const float* __restrict__ w1,
    const float* __restrict__ b1, const float* __restrict__ bn_gamma,
    const float* __restrict__ bn_beta, const float* __restrict__ bn_mean,
    const float* __restrict__ bn_var, const float* __restrict__ w2,
    const float* __restrict__ b2, float* __restrict__ ker)
{
    __shared__ float fs[8][64][36];   // 73.7 KB
    const int tid  = threadIdx.x;
    const int lane = tid & 63;
    const int q    = tid >> 6;        // wave index 0..7
    const int pix  = blockIdx.x * 64 + lane;
    const int b    = pix >> 12;
    const int hw   = pix & 4095;

    const float* xp = x + ((size_t)b * CIN) * HWSZ + hw;

    // wave-uniform weight base, forced scalar
    const float* w1q = w1 + __builtin_amdgcn_readfirstlane(q * 16);

    float f[CR];
#pragma unroll
    for (int o = 0; o < CR; ++o) f[o] = 0.f;

#pragma unroll
    for (int ci = 0; ci < 16; ++ci) {
        const float xv = xp[(size_t)(q * 16 + ci) * HWSZ];   // coalesced
#pragma unroll
        for (int o = 0; o < CR; ++o)
            f[o] += w1q[o * CIN + ci] * xv;                  // s_load weights
    }

#pragma unroll
    for (int o = 0; o < CR; o += 4) {
        float4 v = {f[o], f[o + 1], f[o + 2], f[o + 3]};
        *reinterpret_cast<float4*>(&fs[q][lane][o]) = v;
    }
    __syncthreads();

    // thread (lane, q) reduces o-range [q*4, q*4+4) over the 8 partials
    const int ob = q * 4;
    float4 r = {0.f, 0.f, 0.f, 0.f};
#pragma unroll
    for (int g = 0; g < 8; ++g) {
        const float4 v = *reinterpret_cast<const float4*>(&fs[g][lane][ob]);
        r.x += v.x; r.y += v.y; r.z += v.z; r.w += v.w;
    }
    // BN (eval) + ReLU
    {
        float rr[4] = {r.x, r.y, r.z, r.w};
#pragma unroll
        for (int k = 0; k < 4; ++k) {
            const int o = ob + k;
            const float sc = bn_gamma[o] * rsqrtf(bn_var[o] + 1e-5f);
            const float v  = (rr[k] + b1[o]) * sc + (bn_beta[o] - bn_mean[o] * sc);
            rr[k] = fmaxf(v, 0.f);
        }
        float4 w = {rr[0], rr[1], rr[2], rr[3]};
        *reinterpret_cast<float4*>(&fs[0][lane][ob]) = w;
    }
    __syncthreads();

    // matmul2: fr = fs[0][lane][0..31]; taps split 7,6,6,6,6,6,6,0 by wave
    float fr[CR];
#pragma unroll
    for (int o = 0; o < CR; o += 4) {
        const float4 v = *reinterpret_cast<const float4*>(&fs[0][lane][o]);
        fr[o] = v.x; fr[o + 1] = v.y; fr[o + 2] = v.z; fr[o + 3] = v.w;
    }

    const int p0 = (q == 0) ? 0 : q * 6 + 1;
    const int np = (q == 0) ? 7 : 6;
    const float* w2q = w2 + __builtin_amdgcn_readfirstlane(p0 * CR);
    float* kout = ker + ((size_t)b * KK) * HWSZ + hw;
#pragma unroll
    for (int pi = 0; pi < 7; ++pi) {
        if (pi >= np) break;           // wave-uniform branch
        float s = b2[p0 + pi];
#pragma unroll
        for (int o = 0; o < CR; ++o)
            s += w2q[pi * CR + o] * fr[o];                   // s_load weights
        kout[(size_t)(p0 + pi) * HWSZ] = s;                  // coalesced
    }
}

__device__ __forceinline__ unsigned bf16rne(float f) {
    unsigned u = __float_as_uint(f);
    u += 0x7fffu + ((u >> 16) & 1u);   // round-to-nearest-even
    return u >> 16;
}

// ---------------- Kernel 2: apply the 7x7 gather ---------------------------
// grid 1024 blocks = b(4) x th(4) x tw(4) x csplit(16 of 8 ch)
// -> 4 blocks/CU, 16 waves/CU. Thread = pixel; 49 ker values in VGPRs.
// Halo stored as BF16: one 16B LDS slot per spatial position holds ALL 8
// channels -> 49 ds_read_b128 per thread (was 98 with fp32). Unpack is
// shift/and (bf16->f32 = <<16). LDS time model: 16 waves x 49 x 12cy
// = 9.4k cy/CU ~= 3.9 us (was 7.8).
__global__ __launch_bounds__(256) void inv_gather(
    const float* __restrict__ x, const float* __restrict__ ker,
    float* __restrict__ out)
{
    __shared__ unsigned xs[484 * 4];   // [sp][4 dwords] = 8 bf16 channels

    const int bid = blockIdx.x;
    const int cs  = bid & 15;
    const int tw  = (bid >> 4) & 3;
    const int th  = (bid >> 6) & 3;
    const int b   = bid >> 8;

    const int h0 = th * 16, w0 = tw * 16, c0 = cs * 8;
    const int tid = threadIdx.x;
    const int tx = tid & 15, ty = tid >> 4;
    const int h = h0 + ty, w = w0 + tx;

    // this pixel's 49 kernel values -> VGPRs (reused for all 8 channels)
    float kr[KK];
    const float* kp = ker + ((size_t)b * KK) * HWSZ + h * WW + w;
#pragma unroll
    for (int p = 0; p < KK; ++p) kr[p] = kp[(size_t)p * HWSZ];

    const size_t xbase = (size_t)b * CIN * HWSZ + (size_t)c0 * HWSZ;

    // stage halo: 484 positions, 8 channels each, packed bf16 pairs
    for (int sp = tid; sp < 484; sp += 256) {
        const int row = sp / 22;           // magic-mul (constant divisor)
        const int col = sp - row * 22;
        const int gr = h0 - 3 + row;
        const int gc = w0 - 3 + col;
        uint4 pk = {0u, 0u, 0u, 0u};
        if ((unsigned)gr < 64u && (unsigned)gc < 64u) {
            const float* xp = &x[xbase + gr * WW + gc];
            float v[8];
#pragma unroll
            for (int c = 0; c < 8; ++c) v[c] = xp[(size_t)c * HWSZ];
            unsigned* pw = reinterpret_cast<unsigned*>(&pk);
#pragma unroll
            for (int c = 0; c < 4; ++c)
                pw[c] = bf16rne(v[2 * c]) | (bf16rne(v[2 * c + 1]) << 16);
        }
        *reinterpret_cast<uint4*>(&xs[sp * 4]) = pk;
    }
    __syncthreads();

    float a0 = 0.f, a1 = 0.f, a2 = 0.f, a3 = 0.f;
    float a4 = 0.f, a5 = 0.f, a6 = 0.f, a7 = 0.f;
    const int spbase = ty * 22 + tx;
#pragma unroll
    for (int i = 0; i < KS; ++i) {
#pragma unroll
        for (int j = 0; j < KS; ++j) {
            const int sp = spbase + i * 22 + j;
            const float k = kr[i * KS + j];
            const uint4 d = *reinterpret_cast<const uint4*>(&xs[sp * 4]);
            // bf16 -> f32: even ch = dword<<16, odd ch = dword & 0xffff0000
            a0 += k * __uint_as_float(d.x << 16);
            a1 += k * __uint_as_float(d.x & 0xffff0000u);
            a2 += k * __uint_as_float(d.y << 16);
            a3 += k * __uint_as_float(d.y & 0xffff0000u);
            a4 += k * __uint_as_float(d.z << 16);
            a5 += k * __uint_as_float(d.z & 0xffff0000u);
            a6 += k * __uint_as_float(d.w << 16);
            a7 += k * __uint_as_float(d.w & 0xffff0000u);
        }
    }

    const size_t obase = xbase + h * WW + w;
    out[obase]            = a0;
    out[obase + HWSZ]     = a1;
    out[obase + 2 * HWSZ] = a2;
    out[obase + 3 * HWSZ] = a3;
    out[obase + 4 * HWSZ] = a4;
    out[obase + 5 * HWSZ] = a5;
    out[obase + 6 * HWSZ] = a6;
    out[obase + 7 * HWSZ] = a7;
}

extern "C" void kernel_launch(void* const* d_in, const int* in_sizes, int n_in,
                              void* d_out, int out_size, void* d_ws, size_t ws_size,
                              hipStream_t stream) {
    const float* x        = (const float*)d_in[0];
    const float* w1       = (const float*)d_in[1];
    const float* b1       = (const float*)d_in[2];
    const float* bn_gamma = (const float*)d_in[3];
    const float* bn_beta  = (const float*)d_in[4];
    const float* bn_mean  = (const float*)d_in[5];
    const float* bn_var   = (const float*)d_in[6];
    const float* w2       = (const float*)d_in[7];
    const float* b2       = (const float*)d_in[8];
    float* ker = (float*)d_ws;          // [4,49,64,64] fp32 = 3.2 MB
    float* out = (float*)d_out;

    gen_kernel<<<256, 512, 0, stream>>>(x, w1, b1, bn_gamma, bn_beta,
                                        bn_mean, bn_var, w2, b2, ker);
    inv_gather<<<1024, 256, 0, stream>>>(x, ker, out);
}